// Round 1
// baseline (905.201 us; speedup 1.0000x reference)
//
#include <hip/hip_runtime.h>
#include <math.h>

// SpatialAttention: n=4, c=128, hw=4096 (fp32).
// scores[s,t] = sum_c K[c,s]*Q[c,t] / sqrt(128); softmax over s; out[e,t] = sum_s V[e,s]*P[s,t].
// Flash-style: one block per (batch, 64-wide t tile); stream s in 64-wide chunks.
// fp32 vector FMA (no fp32 MFMA on CDNA4). Roofline ~219us; expect ~300-450us.

#define CC   128   // channels
#define HWSZ 4096  // tokens
#define BT   64    // t-tile
#define BS   64    // s-chunk
#define VP   68    // sV row pitch (floats, %4==0 for 16B-aligned float4 rows)
#define PP   68    // sP row pitch

__global__ __launch_bounds__(256, 1)
void spatial_attn_kernel(const float* __restrict__ Kg, const float* __restrict__ Qg,
                         const float* __restrict__ Vg, float* __restrict__ Og) {
  __shared__ __align__(16) float sQ[CC][BT];   // 32 KB, Q[c][t]
  __shared__ __align__(16) float sK[CC][BS];   // 32 KB, K[c][s]
  __shared__ __align__(16) float sV[CC][VP];   // 34 KB, V[e][s]
  __shared__ __align__(16) float sP[BT][PP];   // 17 KB, P stored TRANSPOSED: sP[t][s]
  __shared__ __align__(16) float sRed[8][BT];  // rows 0..3: partial max, 4..7: partial sum
  __shared__ __align__(16) float sM[BT];       // running max per t
  __shared__ __align__(16) float sL[BT];       // running denom per t
  __shared__ __align__(16) float sAl[BT];      // per-chunk rescale alpha per t

  const int tid = threadIdx.x;
  const int b   = blockIdx.x >> 6;           // / (HWSZ/BT)
  const int tt0 = (blockIdx.x & 63) << 6;    // t-tile origin

  const float* Kb = Kg + (size_t)b * CC * HWSZ;
  const float* Qb = Qg + (size_t)b * CC * HWSZ;
  const float* Vb = Vg + (size_t)b * CC * HWSZ;
  float*       Ob = Og + (size_t)b * CC * HWSZ;

  // thread maps
  const int f4 = tid & 15;   // loader: float4 column
  const int lr = tid >> 4;   // loader: row base (16 rows per pass)
  const int tt = tid & 15;   // S-phase: t quad   (t = 4*tt + ti)
  const int ts = tid >> 4;   // S-phase: s quad   (s = 4*ts + si)
  const int pe = tid & 15;   // PV: e base        (e = pe + 16*i)  -> 2-way bank alias only
  const int pt = tid >> 4;   // PV: t quad        (t = 4*pt + k)
  const int st = tid & 63;   // softmax: t
  const int sp = tid >> 6;   // softmax: part (16 s each)

  // stage Q tile (persistent for the whole block)
  #pragma unroll
  for (int p = 0; p < CC / 16; ++p) {
    const int c = lr + 16 * p;
    *(float4*)&sQ[c][4 * f4] = *(const float4*)(Qb + (size_t)c * HWSZ + tt0 + 4 * f4);
  }
  if (tid < BT) { sM[tid] = -INFINITY; sL[tid] = 0.0f; }

  float accO[8][4];
  #pragma unroll
  for (int i = 0; i < 8; ++i) {
    #pragma unroll
    for (int k = 0; k < 4; ++k) accO[i][k] = 0.0f;
  }

  const float scale = 0.08838834764831845f;  // 1/sqrt(128)

  for (int s0 = 0; s0 < HWSZ; s0 += BS) {
    __syncthreads();  // previous chunk's PV readers done; iter0: Q/sM/sL init visible

    // stage K,V chunks (coalesced float4)
    #pragma unroll
    for (int p = 0; p < CC / 16; ++p) {
      const int c = lr + 16 * p;
      *(float4*)&sK[c][4 * f4] = *(const float4*)(Kb + (size_t)c * HWSZ + s0 + 4 * f4);
      *(float4*)&sV[c][4 * f4] = *(const float4*)(Vb + (size_t)c * HWSZ + s0 + 4 * f4);
    }
    __syncthreads();

    // ---- S = K^T Q (64x64), 4s x 4t micro-tile per thread ----
    float acc[4][4];
    #pragma unroll
    for (int i = 0; i < 4; ++i) {
      #pragma unroll
      for (int j = 0; j < 4; ++j) acc[i][j] = 0.0f;
    }
    #pragma unroll 8
    for (int c = 0; c < CC; ++c) {
      const float4 kk = *(const float4*)&sK[c][4 * ts];
      const float4 qq = *(const float4*)&sQ[c][4 * tt];
      acc[0][0] += kk.x * qq.x; acc[0][1] += kk.x * qq.y; acc[0][2] += kk.x * qq.z; acc[0][3] += kk.x * qq.w;
      acc[1][0] += kk.y * qq.x; acc[1][1] += kk.y * qq.y; acc[1][2] += kk.y * qq.z; acc[1][3] += kk.y * qq.w;
      acc[2][0] += kk.z * qq.x; acc[2][1] += kk.z * qq.y; acc[2][2] += kk.z * qq.z; acc[2][3] += kk.z * qq.w;
      acc[3][0] += kk.w * qq.x; acc[3][1] += kk.w * qq.y; acc[3][2] += kk.w * qq.z; acc[3][3] += kk.w * qq.w;
    }
    // write scaled scores, transposed: sP[t][s] (float4 along s)
    #pragma unroll
    for (int ti = 0; ti < 4; ++ti) {
      float4 v;
      v.x = acc[0][ti] * scale; v.y = acc[1][ti] * scale;
      v.z = acc[2][ti] * scale; v.w = acc[3][ti] * scale;
      *(float4*)&sP[4 * tt + ti][4 * ts] = v;
    }
    __syncthreads();

    // ---- online softmax over s (rows of sP), 4 threads per t ----
    float m_part = -INFINITY;
    #pragma unroll
    for (int j = 0; j < 4; ++j) {
      const float4 x = *(const float4*)&sP[st][16 * sp + 4 * j];
      m_part = fmaxf(m_part, fmaxf(fmaxf(x.x, x.y), fmaxf(x.z, x.w)));
    }
    sRed[sp][st] = m_part;
    __syncthreads();

    const float m_old = sM[st];
    const float cmax  = fmaxf(fmaxf(sRed[0][st], sRed[1][st]), fmaxf(sRed[2][st], sRed[3][st]));
    const float m_new = fmaxf(m_old, cmax);  // identical across the 4 parts of a t (benign sM race)
    float psum = 0.0f;
    #pragma unroll
    for (int j = 0; j < 4; ++j) {
      float4 x = *(float4*)&sP[st][16 * sp + 4 * j];
      x.x = __expf(x.x - m_new); x.y = __expf(x.y - m_new);
      x.z = __expf(x.z - m_new); x.w = __expf(x.w - m_new);
      psum += (x.x + x.y) + (x.z + x.w);
      *(float4*)&sP[st][16 * sp + 4 * j] = x;
    }
    sRed[4 + sp][st] = psum;
    if (sp == 0) { sAl[st] = __expf(m_old - m_new); sM[st] = m_new; }
    __syncthreads();

    if (tid < BT) {
      sL[tid] = sL[tid] * sAl[tid] +
                ((sRed[4][tid] + sRed[5][tid]) + (sRed[6][tid] + sRed[7][tid]));
    }

    // ---- rescale O, then O += V * P  (8e x 4t micro-tile) ----
    const float4 alv = *(const float4*)&sAl[4 * pt];
    #pragma unroll
    for (int i = 0; i < 8; ++i) {
      accO[i][0] *= alv.x; accO[i][1] *= alv.y; accO[i][2] *= alv.z; accO[i][3] *= alv.w;
    }
    #pragma unroll 4
    for (int j = 0; j < BS / 4; ++j) {
      float4 pr[4];
      #pragma unroll
      for (int k = 0; k < 4; ++k) pr[k] = *(const float4*)&sP[4 * pt + k][4 * j];
      #pragma unroll
      for (int i = 0; i < 8; ++i) {
        const float4 vv = *(const float4*)&sV[pe + 16 * i][4 * j];
        #pragma unroll
        for (int k = 0; k < 4; ++k) {
          accO[i][k] += vv.x * pr[k].x + vv.y * pr[k].y + vv.z * pr[k].z + vv.w * pr[k].w;
        }
      }
    }
  }

  __syncthreads();
  const float4 lv = *(const float4*)&sL[4 * pt];
  float4 inv;
  inv.x = 1.0f / lv.x; inv.y = 1.0f / lv.y; inv.z = 1.0f / lv.z; inv.w = 1.0f / lv.w;
  #pragma unroll
  for (int i = 0; i < 8; ++i) {
    float4 o;
    o.x = accO[i][0] * inv.x; o.y = accO[i][1] * inv.y;
    o.z = accO[i][2] * inv.z; o.w = accO[i][3] * inv.w;
    *(float4*)(Ob + (size_t)(pe + 16 * i) * HWSZ + tt0 + 4 * pt) = o;
  }
}

extern "C" void kernel_launch(void* const* d_in, const int* in_sizes, int n_in,
                              void* d_out, int out_size, void* d_ws, size_t ws_size,
                              hipStream_t stream) {
  const float* key   = (const float*)d_in[0];
  const float* query = (const float*)d_in[1];
  const float* value = (const float*)d_in[2];
  float* out = (float*)d_out;
  // 4 batches x 64 t-tiles = 256 blocks (1 per CU), 256 threads
  spatial_attn_kernel<<<dim3(4 * 64), dim3(256), 0, stream>>>(key, query, value, out);
}

// Round 2
// 239.354 us; speedup vs baseline: 3.7818x; 3.7818x over previous
//
#include <hip/hip_runtime.h>
#include <math.h>

// SpatialAttention n=4, c=128, hw=4096 fp32 in/out.
// R2: fp16 MFMA flash attention. Prepass converts K^T*scale, Q^T, V to fp16 in ws.
// Main: 256 blocks (b x t-tile64), 256 thr, 16x16x32 f16 MFMA, in-register softmax.
// Fallback to R1 fp32 kernel if ws_size < 12.6 MB.

#define HW 4096
#define CC 128
#define BT 64
#define BS 64
#define KP 136   // sK/sQ row pitch in halfs (272B: 16B-aligned rows, 2-way banks)
#define VPCH 72  // sV/sPT row pitch in halfs (144B: 16B-aligned rows, 2-way banks)

typedef _Float16 half8  __attribute__((ext_vector_type(8)));
typedef _Float16 half2v __attribute__((ext_vector_type(2)));
typedef _Float16 half4v __attribute__((ext_vector_type(4)));
typedef float    float4v __attribute__((ext_vector_type(4)));

// ---------------- prepass: [b][128][4096] f32 -> [b][4096][128] f16 (scaled) ----
__global__ __launch_bounds__(256)
void transpose_to_fp16(const float* __restrict__ in, _Float16* __restrict__ out, float scale) {
  __shared__ float tile[32][65];
  const int bid = blockIdx.x;
  const int c0 = (bid & 3) << 5;          // 4 c-tiles of 32
  const int s0 = ((bid >> 2) & 63) << 6;  // 64 s-tiles of 64
  const int b  = bid >> 8;
  const float* ib = in + (size_t)b * CC * HW;
  _Float16* ob = out + (size_t)b * HW * CC;
  const int j  = threadIdx.x & 63;
  const int i0 = threadIdx.x >> 6;
  #pragma unroll
  for (int p = 0; p < 8; ++p) {
    const int i = p * 4 + i0;
    tile[i][j] = ib[(size_t)(c0 + i) * HW + s0 + j];
  }
  __syncthreads();
  const int j2 = threadIdx.x & 15;
  const int is = threadIdx.x >> 4;
  #pragma unroll
  for (int p = 0; p < 4; ++p) {
    const int s = p * 16 + is;
    half2v h;
    h.x = (_Float16)(tile[2 * j2][s] * scale);
    h.y = (_Float16)(tile[2 * j2 + 1][s] * scale);
    *(half2v*)&ob[(size_t)(s0 + s) * CC + c0 + 2 * j2] = h;
  }
}

// ---------------- prepass: V f32 -> f16, same layout ----------------------------
__global__ __launch_bounds__(256)
void convert_fp16(const float* __restrict__ in, _Float16* __restrict__ out) {
  const int base = (blockIdx.x * 256 + threadIdx.x) * 4;
  const float4v v = *(const float4v*)(in + base);
  half4v h;
  h.x = (_Float16)v.x; h.y = (_Float16)v.y; h.z = (_Float16)v.z; h.w = (_Float16)v.w;
  *(half4v*)(out + base) = h;
}

// ---------------- main fp16 MFMA flash kernel -----------------------------------
__global__ __launch_bounds__(256, 1)
void attn_mfma(const _Float16* __restrict__ KT, const _Float16* __restrict__ QT,
               const _Float16* __restrict__ Vh, float* __restrict__ Og) {
  __shared__ _Float16 sQ[BT][KP];    // Q^T tile [t][c]
  __shared__ _Float16 sK[BS][KP];    // K^T chunk [s][c] (pre-scaled)
  __shared__ _Float16 sV[CC][VPCH];  // V chunk [e][s]
  __shared__ _Float16 sPT[BT][VPCH]; // P transposed [t][s]
  __shared__ float sRedM[2][BT];
  __shared__ float sRedS[2][BT];
  __shared__ float sM[BT], sMn[BT], sL[BT], sAl[BT];

  const int tid  = threadIdx.x;
  const int b    = blockIdx.x >> 6;
  const int tt0  = (blockIdx.x & 63) << 6;
  const int w    = tid >> 6;        // wave 0..3
  const int lane = tid & 63;
  const int q    = lane >> 4;       // quad
  const int tcol = lane & 15;

  const _Float16* KTb = KT + (size_t)b * HW * CC;
  const _Float16* QTb = QT + (size_t)b * HW * CC;
  const _Float16* Vb  = Vh + (size_t)b * CC * HW;
  float* Ob = Og + (size_t)b * CC * HW;

  // stage Q once: 64 rows x 128 halfs = 16 KB, 4 x uint4 per thread
  #pragma unroll
  for (int p = 0; p < 4; ++p) {
    const int linear = p * 256 + tid;
    const int t = linear >> 4, cs = (linear & 15) * 8;
    *(uint4*)&sQ[t][cs] = *(const uint4*)(QTb + (size_t)(tt0 + t) * CC + cs);
  }
  if (tid < BT) { sM[tid] = -1e30f; sL[tid] = 0.0f; }

  // QK tiling: wave = (s-half, t-half); PV tiling: wave = (e-half, t-half)
  const int sbase = (w & 1) * 32;
  const int tbase = (w >> 1) * 32;
  const int ebase = (w & 1) * 64;

  float4v accO[4][2];
  #pragma unroll
  for (int it = 0; it < 4; ++it)
    #pragma unroll
    for (int jt = 0; jt < 2; ++jt) accO[it][jt] = (float4v){0.f, 0.f, 0.f, 0.f};

  // register prefetch of chunk 0
  uint4 rk[4], rv[4];
  #pragma unroll
  for (int p = 0; p < 4; ++p) {
    const int linear = p * 256 + tid;
    rk[p] = *(const uint4*)(KTb + (size_t)(linear >> 4) * CC + (linear & 15) * 8);
    rv[p] = *(const uint4*)(Vb + (size_t)(linear >> 3) * HW + (linear & 7) * 8);
  }

  for (int s0 = 0; s0 < HW; s0 += BS) {
    __syncthreads();  // prev chunk's PV done reading sK/sV (iter0: Q/init visible)
    #pragma unroll
    for (int p = 0; p < 4; ++p) {
      const int linear = p * 256 + tid;
      *(uint4*)&sK[linear >> 4][(linear & 15) * 8] = rk[p];
      *(uint4*)&sV[linear >> 3][(linear & 7) * 8]  = rv[p];
    }
    __syncthreads();

    // prefetch next chunk into regs (overlaps with compute below)
    if (s0 + BS < HW) {
      const int s1 = s0 + BS;
      #pragma unroll
      for (int p = 0; p < 4; ++p) {
        const int linear = p * 256 + tid;
        rk[p] = *(const uint4*)(KTb + (size_t)(s1 + (linear >> 4)) * CC + (linear & 15) * 8);
        rv[p] = *(const uint4*)(Vb + (size_t)(linear >> 3) * HW + s1 + (linear & 7) * 8);
      }
    }

    // ---- QK: S[s][t], wave tile 32s x 32t as 2x2 of 16x16 ----
    float4v acc[2][2];
    #pragma unroll
    for (int is = 0; is < 2; ++is)
      #pragma unroll
      for (int jt = 0; jt < 2; ++jt) acc[is][jt] = (float4v){0.f, 0.f, 0.f, 0.f};
    #pragma unroll
    for (int ks = 0; ks < 4; ++ks) {
      const int kc = 32 * ks + 8 * q;
      const half8 a0 = *(const half8*)&sK[sbase + tcol][kc];
      const half8 a1 = *(const half8*)&sK[sbase + 16 + tcol][kc];
      const half8 b0 = *(const half8*)&sQ[tbase + tcol][kc];
      const half8 b1 = *(const half8*)&sQ[tbase + 16 + tcol][kc];
      acc[0][0] = __builtin_amdgcn_mfma_f32_16x16x32_f16(a0, b0, acc[0][0], 0, 0, 0);
      acc[0][1] = __builtin_amdgcn_mfma_f32_16x16x32_f16(a0, b1, acc[0][1], 0, 0, 0);
      acc[1][0] = __builtin_amdgcn_mfma_f32_16x16x32_f16(a1, b0, acc[1][0], 0, 0, 0);
      acc[1][1] = __builtin_amdgcn_mfma_f32_16x16x32_f16(a1, b1, acc[1][1], 0, 0, 0);
    }

    // ---- in-register column max over this wave's 32 s ----
    float mx[2];
    #pragma unroll
    for (int jt = 0; jt < 2; ++jt) {
      float m0 = fmaxf(fmaxf(acc[0][jt].x, acc[0][jt].y), fmaxf(acc[0][jt].z, acc[0][jt].w));
      float m1 = fmaxf(fmaxf(acc[1][jt].x, acc[1][jt].y), fmaxf(acc[1][jt].z, acc[1][jt].w));
      float m = fmaxf(m0, m1);
      m = fmaxf(m, __shfl_xor(m, 16));
      m = fmaxf(m, __shfl_xor(m, 32));
      mx[jt] = m;
    }
    if (lane < 16) {
      sRedM[w & 1][tbase + tcol]      = mx[0];
      sRedM[w & 1][tbase + 16 + tcol] = mx[1];
    }
    __syncthreads();

    // ---- combine maxes, exponentiate, write P^T, partial sums ----
    float mn[2], mo[2];
    #pragma unroll
    for (int jt = 0; jt < 2; ++jt) {
      const int t = tbase + 16 * jt + tcol;
      const float mc = fmaxf(sRedM[0][t], sRedM[1][t]);
      mo[jt] = sM[t];
      mn[jt] = fmaxf(mo[jt], mc);
    }
    float ps[2] = {0.f, 0.f};
    #pragma unroll
    for (int is = 0; is < 2; ++is) {
      #pragma unroll
      for (int jt = 0; jt < 2; ++jt) {
        const float p0 = __expf(acc[is][jt].x - mn[jt]);
        const float p1 = __expf(acc[is][jt].y - mn[jt]);
        const float p2 = __expf(acc[is][jt].z - mn[jt]);
        const float p3 = __expf(acc[is][jt].w - mn[jt]);
        ps[jt] += (p0 + p1) + (p2 + p3);
        const int trow = tbase + 16 * jt + tcol;
        const int scol = sbase + 16 * is + 4 * q;
        half2v h01, h23;
        h01.x = (_Float16)p0; h01.y = (_Float16)p1;
        h23.x = (_Float16)p2; h23.y = (_Float16)p3;
        *(half2v*)&sPT[trow][scol]     = h01;
        *(half2v*)&sPT[trow][scol + 2] = h23;
      }
    }
    #pragma unroll
    for (int jt = 0; jt < 2; ++jt) {
      ps[jt] += __shfl_xor(ps[jt], 16);
      ps[jt] += __shfl_xor(ps[jt], 32);
    }
    if (lane < 16) {
      sRedS[w & 1][tbase + tcol]      = ps[0];
      sRedS[w & 1][tbase + 16 + tcol] = ps[1];
      if ((w & 1) == 0) {
        #pragma unroll
        for (int jt = 0; jt < 2; ++jt) {
          const int t = tbase + 16 * jt + tcol;
          sAl[t] = __expf(mo[jt] - mn[jt]);
          sMn[t] = mn[jt];
        }
      }
    }
    __syncthreads();

    if (tid < BT) {
      sL[tid] = sL[tid] * sAl[tid] + sRedS[0][tid] + sRedS[1][tid];
      sM[tid] = sMn[tid];
    }

    // ---- PV: O[e][t] += V * P, wave tile 64e x 32t as 4x2 of 16x16 ----
    const float al0 = sAl[tbase + tcol];
    const float al1 = sAl[tbase + 16 + tcol];
    #pragma unroll
    for (int it = 0; it < 4; ++it) {
      accO[it][0].x *= al0; accO[it][0].y *= al0; accO[it][0].z *= al0; accO[it][0].w *= al0;
      accO[it][1].x *= al1; accO[it][1].y *= al1; accO[it][1].z *= al1; accO[it][1].w *= al1;
    }
    #pragma unroll
    for (int ks = 0; ks < 2; ++ks) {
      const int kc = 32 * ks + 8 * q;
      const half8 bp0 = *(const half8*)&sPT[tbase + tcol][kc];
      const half8 bp1 = *(const half8*)&sPT[tbase + 16 + tcol][kc];
      #pragma unroll
      for (int it = 0; it < 4; ++it) {
        const half8 av = *(const half8*)&sV[ebase + 16 * it + tcol][kc];
        accO[it][0] = __builtin_amdgcn_mfma_f32_16x16x32_f16(av, bp0, accO[it][0], 0, 0, 0);
        accO[it][1] = __builtin_amdgcn_mfma_f32_16x16x32_f16(av, bp1, accO[it][1], 0, 0, 0);
      }
    }
  }

  __syncthreads();
  const float li0 = 1.0f / sL[tbase + tcol];
  const float li1 = 1.0f / sL[tbase + 16 + tcol];
  #pragma unroll
  for (int it = 0; it < 4; ++it) {
    #pragma unroll
    for (int jt = 0; jt < 2; ++jt) {
      const float li = jt ? li1 : li0;
      const int t = tt0 + tbase + 16 * jt + tcol;
      const int e0 = ebase + 16 * it + 4 * q;
      Ob[(size_t)(e0 + 0) * HW + t] = accO[it][jt].x * li;
      Ob[(size_t)(e0 + 1) * HW + t] = accO[it][jt].y * li;
      Ob[(size_t)(e0 + 2) * HW + t] = accO[it][jt].z * li;
      Ob[(size_t)(e0 + 3) * HW + t] = accO[it][jt].w * li;
    }
  }
}

// ================= R1 fp32 fallback (verified correct) ==========================
#define VP 68
#define PP 68
__global__ __launch_bounds__(256, 1)
void spatial_attn_kernel(const float* __restrict__ Kg, const float* __restrict__ Qg,
                         const float* __restrict__ Vg, float* __restrict__ Og) {
  __shared__ __align__(16) float sQ[CC][BT];
  __shared__ __align__(16) float sK[CC][BS];
  __shared__ __align__(16) float sV[CC][VP];
  __shared__ __align__(16) float sP[BT][PP];
  __shared__ __align__(16) float sRed[8][BT];
  __shared__ __align__(16) float sM[BT];
  __shared__ __align__(16) float sL[BT];
  __shared__ __align__(16) float sAl[BT];

  const int tid = threadIdx.x;
  const int b   = blockIdx.x >> 6;
  const int tt0 = (blockIdx.x & 63) << 6;

  const float* Kb = Kg + (size_t)b * CC * HW;
  const float* Qb = Qg + (size_t)b * CC * HW;
  const float* Vb = Vg + (size_t)b * CC * HW;
  float*       Ob = Og + (size_t)b * CC * HW;

  const int f4 = tid & 15;
  const int lr = tid >> 4;
  const int tt = tid & 15;
  const int ts = tid >> 4;
  const int pe = tid & 15;
  const int pt = tid >> 4;
  const int st = tid & 63;
  const int sp = tid >> 6;

  #pragma unroll
  for (int p = 0; p < CC / 16; ++p) {
    const int c = lr + 16 * p;
    *(float4*)&sQ[c][4 * f4] = *(const float4*)(Qb + (size_t)c * HW + tt0 + 4 * f4);
  }
  if (tid < BT) { sM[tid] = -INFINITY; sL[tid] = 0.0f; }

  float accO[8][4];
  #pragma unroll
  for (int i = 0; i < 8; ++i)
    #pragma unroll
    for (int k = 0; k < 4; ++k) accO[i][k] = 0.0f;

  const float scale = 0.08838834764831845f;

  for (int s0 = 0; s0 < HW; s0 += BS) {
    __syncthreads();
    #pragma unroll
    for (int p = 0; p < CC / 16; ++p) {
      const int c = lr + 16 * p;
      *(float4*)&sK[c][4 * f4] = *(const float4*)(Kb + (size_t)c * HW + s0 + 4 * f4);
      *(float4*)&sV[c][4 * f4] = *(const float4*)(Vb + (size_t)c * HW + s0 + 4 * f4);
    }
    __syncthreads();

    float acc[4][4];
    #pragma unroll
    for (int i = 0; i < 4; ++i)
      #pragma unroll
      for (int j = 0; j < 4; ++j) acc[i][j] = 0.0f;
    #pragma unroll 8
    for (int c = 0; c < CC; ++c) {
      const float4 kk = *(const float4*)&sK[c][4 * ts];
      const float4 qq = *(const float4*)&sQ[c][4 * tt];
      acc[0][0] += kk.x * qq.x; acc[0][1] += kk.x * qq.y; acc[0][2] += kk.x * qq.z; acc[0][3] += kk.x * qq.w;
      acc[1][0] += kk.y * qq.x; acc[1][1] += kk.y * qq.y; acc[1][2] += kk.y * qq.z; acc[1][3] += kk.y * qq.w;
      acc[2][0] += kk.z * qq.x; acc[2][1] += kk.z * qq.y; acc[2][2] += kk.z * qq.z; acc[2][3] += kk.z * qq.w;
      acc[3][0] += kk.w * qq.x; acc[3][1] += kk.w * qq.y; acc[3][2] += kk.w * qq.z; acc[3][3] += kk.w * qq.w;
    }
    #pragma unroll
    for (int ti = 0; ti < 4; ++ti) {
      float4 v;
      v.x = acc[0][ti] * scale; v.y = acc[1][ti] * scale;
      v.z = acc[2][ti] * scale; v.w = acc[3][ti] * scale;
      *(float4*)&sP[4 * tt + ti][4 * ts] = v;
    }
    __syncthreads();

    float m_part = -INFINITY;
    #pragma unroll
    for (int j = 0; j < 4; ++j) {
      const float4 x = *(const float4*)&sP[st][16 * sp + 4 * j];
      m_part = fmaxf(m_part, fmaxf(fmaxf(x.x, x.y), fmaxf(x.z, x.w)));
    }
    sRed[sp][st] = m_part;
    __syncthreads();

    const float m_old = sM[st];
    const float cmax  = fmaxf(fmaxf(sRed[0][st], sRed[1][st]), fmaxf(sRed[2][st], sRed[3][st]));
    const float m_new = fmaxf(m_old, cmax);
    float psum = 0.0f;
    #pragma unroll
    for (int j = 0; j < 4; ++j) {
      float4 x = *(float4*)&sP[st][16 * sp + 4 * j];
      x.x = __expf(x.x - m_new); x.y = __expf(x.y - m_new);
      x.z = __expf(x.z - m_new); x.w = __expf(x.w - m_new);
      psum += (x.x + x.y) + (x.z + x.w);
      *(float4*)&sP[st][16 * sp + 4 * j] = x;
    }
    sRed[4 + sp][st] = psum;
    if (sp == 0) { sAl[st] = __expf(m_old - m_new); sM[st] = m_new; }
    __syncthreads();

    if (tid < BT) {
      sL[tid] = sL[tid] * sAl[tid] +
                ((sRed[4][tid] + sRed[5][tid]) + (sRed[6][tid] + sRed[7][tid]));
    }

    const float4 alv = *(const float4*)&sAl[4 * pt];
    #pragma unroll
    for (int i = 0; i < 8; ++i) {
      accO[i][0] *= alv.x; accO[i][1] *= alv.y; accO[i][2] *= alv.z; accO[i][3] *= alv.w;
    }
    #pragma unroll 4
    for (int j = 0; j < BS / 4; ++j) {
      float4 pr[4];
      #pragma unroll
      for (int k = 0; k < 4; ++k) pr[k] = *(const float4*)&sP[4 * pt + k][4 * j];
      #pragma unroll
      for (int i = 0; i < 8; ++i) {
        const float4 vv = *(const float4*)&sV[pe + 16 * i][4 * j];
        #pragma unroll
        for (int k = 0; k < 4; ++k) {
          accO[i][k] += vv.x * pr[k].x + vv.y * pr[k].y + vv.z * pr[k].z + vv.w * pr[k].w;
        }
      }
    }
  }

  __syncthreads();
  const float4 lv = *(const float4*)&sL[4 * pt];
  float4 inv;
  inv.x = 1.0f / lv.x; inv.y = 1.0f / lv.y; inv.z = 1.0f / lv.z; inv.w = 1.0f / lv.w;
  #pragma unroll
  for (int i = 0; i < 8; ++i) {
    float4 o;
    o.x = accO[i][0] * inv.x; o.y = accO[i][1] * inv.y;
    o.z = accO[i][2] * inv.z; o.w = accO[i][3] * inv.w;
    *(float4*)(Ob + (size_t)(pe + 16 * i) * HW + tt0 + 4 * pt) = o;
  }
}

extern "C" void kernel_launch(void* const* d_in, const int* in_sizes, int n_in,
                              void* d_out, int out_size, void* d_ws, size_t ws_size,
                              hipStream_t stream) {
  const float* key   = (const float*)d_in[0];
  const float* query = (const float*)d_in[1];
  const float* value = (const float*)d_in[2];
  float* out = (float*)d_out;

  const size_t TEN = (size_t)4 * HW * CC * sizeof(_Float16);  // 4 MiB per fp16 tensor
  if (ws_size >= 3 * TEN) {
    _Float16* KT = (_Float16*)d_ws;
    _Float16* QT = (_Float16*)((char*)d_ws + TEN);
    _Float16* Vh = (_Float16*)((char*)d_ws + 2 * TEN);
    transpose_to_fp16<<<dim3(1024), dim3(256), 0, stream>>>(key, KT, 0.08838834764831845f);
    transpose_to_fp16<<<dim3(1024), dim3(256), 0, stream>>>(query, QT, 1.0f);
    convert_fp16<<<dim3(2048), dim3(256), 0, stream>>>(value, Vh);
    attn_mfma<<<dim3(256), dim3(256), 0, stream>>>(KT, QT, Vh, out);
  } else {
    spatial_attn_kernel<<<dim3(256), dim3(256), 0, stream>>>(key, query, value, out);
  }
}